// Round 2
// baseline (6299.590 us; speedup 1.0000x reference)
//
#include <hip/hip_runtime.h>
#include <cmath>

// Problem constants: B=32, T=1024, J=1024, H=2048
#define BB 32
#define TT 1024
#define JJ 1024
#define HH 2048
#define MM (BB * TT)      // 32768 rows
#define MHALF (MM / 2)    // 16384 rows per half (batches 0..15 | 16..31)

// ---------------- GEMM: C[M,N] = A[M,K] * W[N,K]^T ----------------
// A is f32 (layer 1) or u8 spikes (layers 2,3) — converted exactly in staging.
#define BM 128
#define BN 128
#define BK 16
#define LDS_LD 132   // padded LDS leading dim: 2-way write conflicts only (free)

template <typename AT>
__device__ inline void load_a4(const AT* p, float f[4]) {
    if constexpr (sizeof(AT) == 4) {
        const float4 v = *(const float4*)p;
        f[0] = v.x; f[1] = v.y; f[2] = v.z; f[3] = v.w;
    } else {
        const uchar4 v = *(const uchar4*)p;
        f[0] = (float)v.x; f[1] = (float)v.y; f[2] = (float)v.z; f[3] = (float)v.w;
    }
}

template <typename AT>
__global__ __launch_bounds__(256) void sgemm_bt(
    const AT* __restrict__ A,      // [M,K]
    const float* __restrict__ W,   // [N,K]
    float* __restrict__ C,         // [M,N]
    int M, int N, int K)
{
    __shared__ float As[BK][LDS_LD];
    __shared__ float Bs[BK][LDS_LD];
    const int tid = threadIdx.x;
    const int tx = tid & 15;
    const int ty = tid >> 4;
    const int bm = blockIdx.x * BM;
    const int bn = blockIdx.y * BN;

    float acc[8][8];
#pragma unroll
    for (int i = 0; i < 8; ++i)
#pragma unroll
        for (int j = 0; j < 8; ++j) acc[i][j] = 0.f;

    const int r0 = tid >> 2;          // 0..63
    const int c4 = (tid & 3) * 4;     // 0,4,8,12

    for (int k0 = 0; k0 < K; k0 += BK) {
#pragma unroll
        for (int l = 0; l < 2; ++l) {
            const int r = r0 + l * 64;
            float fa[4];
            load_a4(A + (size_t)(bm + r) * K + k0 + c4, fa);
            As[c4 + 0][r] = fa[0]; As[c4 + 1][r] = fa[1];
            As[c4 + 2][r] = fa[2]; As[c4 + 3][r] = fa[3];
            const float4 vb = *(const float4*)(W + (size_t)(bn + r) * K + k0 + c4);
            Bs[c4 + 0][r] = vb.x; Bs[c4 + 1][r] = vb.y;
            Bs[c4 + 2][r] = vb.z; Bs[c4 + 3][r] = vb.w;
        }
        __syncthreads();
#pragma unroll
        for (int k = 0; k < BK; ++k) {
            float a[8], b[8];
            *(float4*)&a[0] = *(const float4*)&As[k][ty * 8];
            *(float4*)&a[4] = *(const float4*)&As[k][ty * 8 + 4];
            *(float4*)&b[0] = *(const float4*)&Bs[k][tx * 8];
            *(float4*)&b[4] = *(const float4*)&Bs[k][tx * 8 + 4];
#pragma unroll
            for (int i = 0; i < 8; ++i)
#pragma unroll
                for (int j = 0; j < 8; ++j)
                    acc[i][j] = fmaf(a[i], b[j], acc[i][j]);
        }
        __syncthreads();
    }
#pragma unroll
    for (int i = 0; i < 8; ++i) {
        const size_t row = (size_t)(bm + ty * 8 + i) * N + bn + tx * 8;
        *(float4*)(C + row)     = make_float4(acc[i][0], acc[i][1], acc[i][2], acc[i][3]);
        *(float4*)(C + row + 4) = make_float4(acc[i][4], acc[i][5], acc[i][6], acc[i][7]);
    }
}

// ---------------- BatchNorm stats (two-stage, deterministic) ----------------
#define RCHUNK 128   // rows per partial chunk

__global__ void bn_stats_partial(const float* __restrict__ h,   // half/full base
                                 float* __restrict__ partial,   // chunk-offset base
                                 int N)
{
    const int n = blockIdx.x * 256 + threadIdx.x;
    const int chunk = blockIdx.y;
    const float* p = h + (size_t)chunk * RCHUNK * N + n;
    float s = 0.f, s2 = 0.f;
#pragma unroll 4
    for (int r = 0; r < RCHUNK; ++r) {
        const float v = p[(size_t)r * N];
        s += v;
        s2 = fmaf(v, v, s2);
    }
    partial[((size_t)chunk * 2 + 0) * N + n] = s;
    partial[((size_t)chunk * 2 + 1) * N + n] = s2;
}

__global__ void bn_stats_final(const float* __restrict__ partial,
                               float* __restrict__ stats,  // [0..N): mu, [N..2N): rstd
                               int N, int nchunks)
{
    const int n = blockIdx.x * 256 + threadIdx.x;
    double s = 0.0, s2 = 0.0;
    for (int c = 0; c < nchunks; ++c) {
        s  += (double)partial[((size_t)c * 2 + 0) * N + n];
        s2 += (double)partial[((size_t)c * 2 + 1) * N + n];
    }
    const double inv_m = 1.0 / (double)MM;
    const double mu = s * inv_m;
    const double var = s2 * inv_m - mu * mu;     // biased var (matches jnp.var)
    stats[n]     = (float)mu;
    stats[N + n] = (float)(1.0 / sqrt(var + 1e-5));
}

// ---------------- Fused BN-normalize + LIF scan over T ----------------
// h/out/U0 pointers are pre-offset to the batch range; grid.y = #batches here.
template <typename OT>
__global__ void bn_lif_scan(const float* __restrict__ h,   // [nb*T, N]
                            OT* __restrict__ out,          // [nb*T, N]
                            const float* __restrict__ stats,
                            const float* __restrict__ gamma,
                            const float* __restrict__ bias,
                            const float* __restrict__ beta_p,
                            const float* __restrict__ U0,  // [nb, N]
                            int N)
{
    const int n = blockIdx.x * 256 + threadIdx.x;
    const int b = blockIdx.y;
    const float mu = stats[n];
    const float rstd = stats[N + n];
    const float g = gamma[n];
    const float bi = bias[n];
    const float beta = 1.f / (1.f + expf(-beta_p[n]));
    const float omb = 1.f - beta;
    float u = U0[(size_t)b * N + n];
    float s = 0.f;
    size_t idx = ((size_t)b * TT) * N + n;
    for (int t = 0; t < TT; ++t, idx += N) {
        const float hn = (h[idx] - mu) * rstd * g + bi;
        u = beta * (u - s) + omb * hn;
        s = (u - 1.0f >= 0.f) ? 1.f : 0.f;
        out[idx] = (OT)s;
    }
}

// ---------------- launcher ----------------
extern "C" void kernel_launch(void* const* d_in, const int* in_sizes, int n_in,
                              void* d_out, int out_size, void* d_ws, size_t ws_size,
                              hipStream_t stream)
{
    const float* x   = (const float*)d_in[0];
    const float* W1  = (const float*)d_in[1];
    const float* bp1 = (const float*)d_in[2];
    const float* g1  = (const float*)d_in[3];
    const float* bi1 = (const float*)d_in[4];
    const float* U01 = (const float*)d_in[5];
    const float* W2  = (const float*)d_in[6];
    const float* bp2 = (const float*)d_in[7];
    const float* g2  = (const float*)d_in[8];
    const float* bi2 = (const float*)d_in[9];
    const float* U02 = (const float*)d_in[10];
    const float* W3  = (const float*)d_in[11];
    const float* bp3 = (const float*)d_in[12];
    const float* g3  = (const float*)d_in[13];
    const float* bi3 = (const float*)d_in[14];
    const float* U03 = (const float*)d_in[15];
    float* out = (float*)d_out;

    // Workspace layout (total ~206 MB; h is split across ws-half + d_out):
    //   [0, 134MB)          h half0 (batches 0..15) f32 [MHALF, 2048]
    //   [134MB, 201MB)      spikes u8 [MM, 2048]
    //   [201MB, 205MB)      BN partials (256 chunks x 2 x N)
    //   [205MB, +16KB)      BN stats (mu, rstd)
    const size_t HHALF_BYTES = (size_t)MHALF * HH * sizeof(float);  // 134,217,728
    float*         hA   = (float*)d_ws;
    float*         hB   = (float*)d_out;   // d_out doubles as h half1; overwritten by layer 3
    unsigned char* spk  = (unsigned char*)d_ws + HHALF_BYTES;
    float*         part = (float*)((unsigned char*)d_ws + HHALF_BYTES + (size_t)MM * HH);
    float*         stat = part + (size_t)(MM / RCHUNK) * 2 * HH;

    const dim3 blk(256);
    const int nck  = MM / RCHUNK;       // 256 chunks total
    const int nckH = MHALF / RCHUNK;    // 128 per half

    // ================= Layer 1: x[M,J] * W1[H,J]^T =================
    sgemm_bt<float><<<dim3(MHALF / BM, HH / BN), blk, 0, stream>>>(x, W1, hA, MHALF, HH, JJ);
    sgemm_bt<float><<<dim3(MHALF / BM, HH / BN), blk, 0, stream>>>(
        x + (size_t)MHALF * JJ, W1, hB, MHALF, HH, JJ);
    bn_stats_partial<<<dim3(HH / 256, nckH), blk, 0, stream>>>(hA, part, HH);
    bn_stats_partial<<<dim3(HH / 256, nckH), blk, 0, stream>>>(hB, part + (size_t)nckH * 2 * HH, HH);
    bn_stats_final<<<dim3(HH / 256), blk, 0, stream>>>(part, stat, HH, nck);
    bn_lif_scan<unsigned char><<<dim3(HH / 256, BB / 2), blk, 0, stream>>>(
        hA, spk, stat, g1, bi1, bp1, U01, HH);
    bn_lif_scan<unsigned char><<<dim3(HH / 256, BB / 2), blk, 0, stream>>>(
        hB, spk + (size_t)MHALF * HH, stat, g1, bi1, bp1, U01 + (size_t)(BB / 2) * HH, HH);

    // ================= Layer 2: spk[M,H] * W2[H,H]^T =================
    sgemm_bt<unsigned char><<<dim3(MHALF / BM, HH / BN), blk, 0, stream>>>(spk, W2, hA, MHALF, HH, HH);
    sgemm_bt<unsigned char><<<dim3(MHALF / BM, HH / BN), blk, 0, stream>>>(
        spk + (size_t)MHALF * HH, W2, hB, MHALF, HH, HH);
    bn_stats_partial<<<dim3(HH / 256, nckH), blk, 0, stream>>>(hA, part, HH);
    bn_stats_partial<<<dim3(HH / 256, nckH), blk, 0, stream>>>(hB, part + (size_t)nckH * 2 * HH, HH);
    bn_stats_final<<<dim3(HH / 256), blk, 0, stream>>>(part, stat, HH, nck);
    bn_lif_scan<unsigned char><<<dim3(HH / 256, BB / 2), blk, 0, stream>>>(
        hA, spk, stat, g2, bi2, bp2, U02, HH);
    bn_lif_scan<unsigned char><<<dim3(HH / 256, BB / 2), blk, 0, stream>>>(
        hB, spk + (size_t)MHALF * HH, stat, g2, bi2, bp2, U02 + (size_t)(BB / 2) * HH, HH);

    // ================= Layer 3: spk[M,H] * W3[J,H]^T =================
    // h3 [M,1024] f32 = 134MB fits entirely in the hA region of ws.
    sgemm_bt<unsigned char><<<dim3(MM / BM, JJ / BN), blk, 0, stream>>>(spk, W3, hA, MM, JJ, HH);
    bn_stats_partial<<<dim3(JJ / 256, nck), blk, 0, stream>>>(hA, part, JJ);
    bn_stats_final<<<dim3(JJ / 256), blk, 0, stream>>>(part, stat, JJ, nck);
    bn_lif_scan<float><<<dim3(JJ / 256, BB), blk, 0, stream>>>(
        hA, out, stat, g3, bi3, bp3, U03, JJ);
}

// Round 3
// 5238.118 us; speedup vs baseline: 1.2026x; 1.2026x over previous
//
#include <hip/hip_runtime.h>
#include <hip/hip_bf16.h>
#include <cmath>

// Problem constants: B=32, T=1024, J=1024, H=2048
#define BB 32
#define TT 1024
#define JJ 1024
#define HH 2048
#define MM (BB * TT)      // 32768 rows
#define MHALF (MM / 2)    // 16384 rows per half (batches 0..15 | 16..31)

typedef short s8v __attribute__((ext_vector_type(8)));   // 8 bf16 raw bits
typedef float f4v __attribute__((ext_vector_type(4)));
typedef unsigned int u4v __attribute__((ext_vector_type(4)));
union ABu { u4v u; s8v v; };

// ================= exact f32 -> bf16x3 split (w == hi+mid+lo exactly) =====
__global__ void split_w(const float* __restrict__ W,
                        unsigned short* __restrict__ ph,
                        unsigned short* __restrict__ pm,
                        unsigned short* __restrict__ pl, int n)
{
    const int i = blockIdx.x * 256 + threadIdx.x;
    if (i >= n) return;
    const float w = W[i];
    __hip_bfloat16 bh = __float2bfloat16(w);
    const float fh = __bfloat162float(bh);
    const float r1 = w - fh;                    // exact (<=16 significant bits)
    __hip_bfloat16 bm = __float2bfloat16(r1);
    const float fm = __bfloat162float(bm);
    __hip_bfloat16 bl = __float2bfloat16(r1 - fm);  // exact residual
    ph[i] = *(unsigned short*)&bh;
    pm[i] = *(unsigned short*)&bm;
    pl[i] = *(unsigned short*)&bl;
}

// ================= MFMA GEMM: C[M,N] f32 = spikes[M,K](bits) * W[N,K]^T ===
// W given as 3 exact bf16 planes; all three accumulate into one f32 acc.
__global__ __launch_bounds__(256) void mfma_spk_gemm(
    const unsigned char* __restrict__ S,    // [M, K/8] bit-packed spikes
    const unsigned short* __restrict__ Wh,  // [N,K] bf16 raw
    const unsigned short* __restrict__ Wm,
    const unsigned short* __restrict__ Wl,
    float* __restrict__ C, int M, int N, int K)
{
    __shared__ __align__(16) unsigned short Blds[3][128][32];  // 24 KB, chunk-swizzled
    const int tid = threadIdx.x;
    const int wv = tid >> 6;            // wave 0..3
    const int lane = tid & 63;
    const int wm = wv >> 1, wn = wv & 1;
    const int r16 = lane & 15, quad = lane >> 4;
    const int bm = blockIdx.x * 128;
    const int bn = blockIdx.y * 128;
    const int Kb = K >> 3;

    f4v acc[4][4] = {};   // [msub][nsub], C/D layout: col=lane&15, row=quad*4+reg

    // global_load_lds staging: wave wv covers B-tile rows [wv*32, wv*32+32),
    // 2 issues x 1024B. Lane l -> LDS byte l*16 -> (row=l>>2, chunk=l&3).
    // Swizzle: chunk ch at row r holds k-chunk kc = (ch - (r>>1)) & 3.
    const int rl = lane >> 2, chl = lane & 3;
    size_t soff[2];
    int ldsrow[2];
#pragma unroll
    for (int i = 0; i < 2; ++i) {
        const int r = wv * 32 + i * 16 + rl;
        const int kc = (chl - (r >> 1)) & 3;
        soff[i] = (size_t)(bn + r) * K + kc * 8;   // ushort units
        ldsrow[i] = wv * 32 + i * 16;
    }

    // A: direct-from-global bit-packed bytes; A-frag layout m=lane&15, k=quad*8+j
    size_t aoff[4];
#pragma unroll
    for (int ms = 0; ms < 4; ++ms)
        aoff[ms] = (size_t)(bm + wm * 64 + ms * 16 + r16) * Kb + quad;

    // B-frag LDS coords; B layout: n=lane&15, k=quad*8+j (reader applies swizzle)
    int bR[4], bC[4];
#pragma unroll
    for (int ns = 0; ns < 4; ++ns) {
        bR[ns] = wn * 64 + ns * 16 + r16;
        bC[ns] = ((quad + (bR[ns] >> 1)) & 3) * 8;
    }

    for (int k0 = 0; k0 < K; k0 += 32) {
        __syncthreads();   // prior iteration's ds_reads complete
#pragma unroll
        for (int i = 0; i < 2; ++i) {
            __builtin_amdgcn_global_load_lds(
                (const __attribute__((address_space(1))) void*)(Wh + soff[i] + k0),
                (__attribute__((address_space(3))) void*)&Blds[0][ldsrow[i]][0], 16, 0, 0);
            __builtin_amdgcn_global_load_lds(
                (const __attribute__((address_space(1))) void*)(Wm + soff[i] + k0),
                (__attribute__((address_space(3))) void*)&Blds[1][ldsrow[i]][0], 16, 0, 0);
            __builtin_amdgcn_global_load_lds(
                (const __attribute__((address_space(1))) void*)(Wl + soff[i] + k0),
                (__attribute__((address_space(3))) void*)&Blds[2][ldsrow[i]][0], 16, 0, 0);
        }
        unsigned int ab[4];
        const int kb = k0 >> 3;
#pragma unroll
        for (int ms = 0; ms < 4; ++ms) ab[ms] = S[aoff[ms] + kb];
        __syncthreads();   // staging visible (vmcnt drained per-wave at barrier)

        s8v afr[4];
#pragma unroll
        for (int ms = 0; ms < 4; ++ms) {   // unpack 8 spike bits -> 8 bf16 (raw)
            ABu t;
            const unsigned int b = ab[ms];
            t.u[0] = ((b        & 1u) * 0x3F80u) | (((b >> 1) & 1u) * 0x3F800000u);
            t.u[1] = (((b >> 2) & 1u) * 0x3F80u) | (((b >> 3) & 1u) * 0x3F800000u);
            t.u[2] = (((b >> 4) & 1u) * 0x3F80u) | (((b >> 5) & 1u) * 0x3F800000u);
            t.u[3] = (((b >> 6) & 1u) * 0x3F80u) | (((b >> 7) & 1u) * 0x3F800000u);
            afr[ms] = t.v;
        }
#pragma unroll
        for (int p = 0; p < 3; ++p) {
            s8v bf[4];
#pragma unroll
            for (int ns = 0; ns < 4; ++ns)
                bf[ns] = *(const s8v*)&Blds[p][bR[ns]][bC[ns]];
#pragma unroll
            for (int ms = 0; ms < 4; ++ms)
#pragma unroll
                for (int ns = 0; ns < 4; ++ns)
                    acc[ms][ns] = __builtin_amdgcn_mfma_f32_16x16x32_bf16(
                        afr[ms], bf[ns], acc[ms][ns], 0, 0, 0);
        }
    }

#pragma unroll
    for (int ms = 0; ms < 4; ++ms)
#pragma unroll
        for (int ns = 0; ns < 4; ++ns) {
            const int row = bm + wm * 64 + ms * 16 + quad * 4;
            const int col = bn + wn * 64 + ns * 16 + r16;
#pragma unroll
            for (int r = 0; r < 4; ++r)
                C[(size_t)(row + r) * N + col] = acc[ms][ns][r];
        }
}

// ================= f32 SGEMM for layer 1 (x is arbitrary f32) =============
#define BM 128
#define BN 128
#define BK 16
#define LDS_LD 132

__global__ __launch_bounds__(256) void sgemm_bt(
    const float* __restrict__ A,   // [M,K]
    const float* __restrict__ W,   // [N,K]
    float* __restrict__ C,         // [M,N]
    int M, int N, int K)
{
    __shared__ float As[BK][LDS_LD];
    __shared__ float Bs[BK][LDS_LD];
    const int tid = threadIdx.x;
    const int tx = tid & 15;
    const int ty = tid >> 4;
    const int bm = blockIdx.x * BM;
    const int bn = blockIdx.y * BN;

    float acc[8][8];
#pragma unroll
    for (int i = 0; i < 8; ++i)
#pragma unroll
        for (int j = 0; j < 8; ++j) acc[i][j] = 0.f;

    const int r0 = tid >> 2;
    const int c4 = (tid & 3) * 4;

    for (int k0 = 0; k0 < K; k0 += BK) {
#pragma unroll
        for (int l = 0; l < 2; ++l) {
            const int r = r0 + l * 64;
            const float4 va = *(const float4*)(A + (size_t)(bm + r) * K + k0 + c4);
            As[c4 + 0][r] = va.x; As[c4 + 1][r] = va.y;
            As[c4 + 2][r] = va.z; As[c4 + 3][r] = va.w;
            const float4 vb = *(const float4*)(W + (size_t)(bn + r) * K + k0 + c4);
            Bs[c4 + 0][r] = vb.x; Bs[c4 + 1][r] = vb.y;
            Bs[c4 + 2][r] = vb.z; Bs[c4 + 3][r] = vb.w;
        }
        __syncthreads();
#pragma unroll
        for (int k = 0; k < BK; ++k) {
            float a[8], b[8];
            *(float4*)&a[0] = *(const float4*)&As[k][ty * 8];
            *(float4*)&a[4] = *(const float4*)&As[k][ty * 8 + 4];
            // column split tx*4 / 64+tx*4: 2-way banks (free) instead of 4-way
            *(float4*)&b[0] = *(const float4*)&Bs[k][tx * 4];
            *(float4*)&b[4] = *(const float4*)&Bs[k][64 + tx * 4];
#pragma unroll
            for (int i = 0; i < 8; ++i)
#pragma unroll
                for (int j = 0; j < 8; ++j)
                    acc[i][j] = fmaf(a[i], b[j], acc[i][j]);
        }
        __syncthreads();
    }
#pragma unroll
    for (int i = 0; i < 8; ++i) {
        const size_t row = (size_t)(bm + ty * 8 + i) * N;
        *(float4*)(C + row + bn + tx * 4)      = make_float4(acc[i][0], acc[i][1], acc[i][2], acc[i][3]);
        *(float4*)(C + row + bn + 64 + tx * 4) = make_float4(acc[i][4], acc[i][5], acc[i][6], acc[i][7]);
    }
}

// ================= BatchNorm stats (two-stage, deterministic) =============
#define RCHUNK 128

__global__ void bn_stats_partial(const float* __restrict__ h,
                                 float* __restrict__ partial, int N)
{
    const int n = blockIdx.x * 256 + threadIdx.x;
    const int chunk = blockIdx.y;
    const float* p = h + (size_t)chunk * RCHUNK * N + n;
    float s = 0.f, s2 = 0.f;
#pragma unroll 4
    for (int r = 0; r < RCHUNK; ++r) {
        const float v = p[(size_t)r * N];
        s += v;
        s2 = fmaf(v, v, s2);
    }
    partial[((size_t)chunk * 2 + 0) * N + n] = s;
    partial[((size_t)chunk * 2 + 1) * N + n] = s2;
}

__global__ void bn_stats_final(const float* __restrict__ partial,
                               float* __restrict__ stats,
                               int N, int nchunks)
{
    const int n = blockIdx.x * 256 + threadIdx.x;
    double s = 0.0, s2 = 0.0;
    for (int c = 0; c < nchunks; ++c) {
        s  += (double)partial[((size_t)c * 2 + 0) * N + n];
        s2 += (double)partial[((size_t)c * 2 + 1) * N + n];
    }
    const double inv_m = 1.0 / (double)MM;
    const double mu = s * inv_m;
    const double var = s2 * inv_m - mu * mu;
    stats[n]     = (float)mu;
    stats[N + n] = (float)(1.0 / sqrt(var + 1e-5));
}

// ================= fused BN + LIF scan, bit-packed spike output ===========
__global__ void bn_lif_scan_pack(const float* __restrict__ h,       // [nb*T, N]
                                 unsigned long long* __restrict__ bits, // [nb*T, N/64]
                                 const float* __restrict__ stats,
                                 const float* __restrict__ gamma,
                                 const float* __restrict__ bias,
                                 const float* __restrict__ beta_p,
                                 const float* __restrict__ U0,      // [nb, N]
                                 int N)
{
    const int n = blockIdx.x * 256 + threadIdx.x;
    const int b = blockIdx.y;
    const int nw = N >> 6;
    const float mu = stats[n];
    const float rstd = stats[N + n];
    const float g = gamma[n];
    const float bi = bias[n];
    const float beta = 1.f / (1.f + expf(-beta_p[n]));
    const float omb = 1.f - beta;
    float u = U0[(size_t)b * N + n];
    float s = 0.f;
    size_t idx = ((size_t)b * TT) * N + n;
    size_t widx = ((size_t)b * TT) * nw + (n >> 6);
    const bool lead = (threadIdx.x & 63) == 0;
    for (int t = 0; t < TT; ++t, idx += N, widx += nw) {
        const float hn = (h[idx] - mu) * rstd * g + bi;
        u = beta * (u - s) + omb * hn;
        const bool sp = (u - 1.0f) >= 0.f;
        s = sp ? 1.f : 0.f;
        const unsigned long long m = __ballot(sp);
        if (lead) bits[widx] = m;
    }
}

// f32-output variant for the final layer
__global__ void bn_lif_scan_f32(const float* __restrict__ h,
                                float* __restrict__ out,
                                const float* __restrict__ stats,
                                const float* __restrict__ gamma,
                                const float* __restrict__ bias,
                                const float* __restrict__ beta_p,
                                const float* __restrict__ U0,
                                int N)
{
    const int n = blockIdx.x * 256 + threadIdx.x;
    const int b = blockIdx.y;
    const float mu = stats[n];
    const float rstd = stats[N + n];
    const float g = gamma[n];
    const float bi = bias[n];
    const float beta = 1.f / (1.f + expf(-beta_p[n]));
    const float omb = 1.f - beta;
    float u = U0[(size_t)b * N + n];
    float s = 0.f;
    size_t idx = ((size_t)b * TT) * N + n;
    for (int t = 0; t < TT; ++t, idx += N) {
        const float hn = (h[idx] - mu) * rstd * g + bi;
        u = beta * (u - s) + omb * hn;
        s = ((u - 1.0f) >= 0.f) ? 1.f : 0.f;
        out[idx] = s;
    }
}

// ================= launcher ===============================================
extern "C" void kernel_launch(void* const* d_in, const int* in_sizes, int n_in,
                              void* d_out, int out_size, void* d_ws, size_t ws_size,
                              hipStream_t stream)
{
    const float* x   = (const float*)d_in[0];
    const float* W1  = (const float*)d_in[1];
    const float* bp1 = (const float*)d_in[2];
    const float* g1  = (const float*)d_in[3];
    const float* bi1 = (const float*)d_in[4];
    const float* U01 = (const float*)d_in[5];
    const float* W2  = (const float*)d_in[6];
    const float* bp2 = (const float*)d_in[7];
    const float* g2  = (const float*)d_in[8];
    const float* bi2 = (const float*)d_in[9];
    const float* U02 = (const float*)d_in[10];
    const float* W3  = (const float*)d_in[11];
    const float* bp3 = (const float*)d_in[12];
    const float* g3  = (const float*)d_in[13];
    const float* bi3 = (const float*)d_in[14];
    const float* U03 = (const float*)d_in[15];
    float* out = (float*)d_out;

    // ws layout (~184.6 MB total, all 16B-aligned):
    //   hA       f32  [16384,2048] (half-h) / [32768,1024] (L3 h)   134 MB
    //   spk bits      [32768, 2048/64] ull                            8 MB
    //   partials f32  256 chunks x 2 x N                              4 MB
    //   stats    f32  2 x N                                          16 KB
    //   W2 planes bf16 x3                                            24 MB
    //   W3 planes bf16 x3                                            12 MB
    unsigned char* ws = (unsigned char*)d_ws;
    const size_t HA_BYTES = (size_t)MHALF * HH * sizeof(float);      // 134217728
    float*              hA   = (float*)ws;
    float*              hB   = (float*)d_out;  // d_out = 134 MB scratch until final scan
    unsigned long long* spk  = (unsigned long long*)(ws + HA_BYTES);
    const size_t SPK_BYTES = (size_t)MM * (HH / 8);                  // 8388608
    float*              part = (float*)(ws + HA_BYTES + SPK_BYTES);
    float*              stat = (float*)(ws + HA_BYTES + SPK_BYTES + 4194304);
    unsigned short*     W2h  = (unsigned short*)(ws + HA_BYTES + SPK_BYTES + 4194304 + 16384);
    unsigned short*     W2m  = W2h + (size_t)HH * HH;
    unsigned short*     W2l  = W2m + (size_t)HH * HH;
    unsigned short*     W3h  = W2l + (size_t)HH * HH;
    unsigned short*     W3m  = W3h + (size_t)JJ * HH;
    unsigned short*     W3l  = W3m + (size_t)JJ * HH;

    const dim3 blk(256);
    const int nck  = MM / RCHUNK;      // 256
    const int nckH = MHALF / RCHUNK;   // 128

    // ---- pre-split weights into exact bf16 triples ----
    split_w<<<dim3((HH * HH) / 256), blk, 0, stream>>>(W2, W2h, W2m, W2l, HH * HH);
    split_w<<<dim3((JJ * HH) / 256), blk, 0, stream>>>(W3, W3h, W3m, W3l, JJ * HH);

    // ================= Layer 1: x[M,J] * W1[H,J]^T (f32 vector GEMM) ======
    sgemm_bt<<<dim3(MHALF / BM, HH / BN), blk, 0, stream>>>(x, W1, hA, MHALF, HH, JJ);
    sgemm_bt<<<dim3(MHALF / BM, HH / BN), blk, 0, stream>>>(
        x + (size_t)MHALF * JJ, W1, hB, MHALF, HH, JJ);
    bn_stats_partial<<<dim3(HH / 256, nckH), blk, 0, stream>>>(hA, part, HH);
    bn_stats_partial<<<dim3(HH / 256, nckH), blk, 0, stream>>>(hB, part + (size_t)nckH * 2 * HH, HH);
    bn_stats_final<<<dim3(HH / 256), blk, 0, stream>>>(part, stat, HH, nck);
    bn_lif_scan_pack<<<dim3(HH / 256, BB / 2), blk, 0, stream>>>(
        hA, spk, stat, g1, bi1, bp1, U01, HH);
    bn_lif_scan_pack<<<dim3(HH / 256, BB / 2), blk, 0, stream>>>(
        hB, spk + (size_t)MHALF * (HH / 64), stat, g1, bi1, bp1, U01 + (size_t)(BB / 2) * HH, HH);

    // ================= Layer 2: spk[M,H] * W2[H,H]^T (MFMA bf16x3) =======
    mfma_spk_gemm<<<dim3(MHALF / 128, HH / 128), blk, 0, stream>>>(
        (const unsigned char*)spk, W2h, W2m, W2l, hA, MHALF, HH, HH);
    mfma_spk_gemm<<<dim3(MHALF / 128, HH / 128), blk, 0, stream>>>(
        (const unsigned char*)spk + (size_t)MHALF * (HH / 8), W2h, W2m, W2l, hB, MHALF, HH, HH);
    bn_stats_partial<<<dim3(HH / 256, nckH), blk, 0, stream>>>(hA, part, HH);
    bn_stats_partial<<<dim3(HH / 256, nckH), blk, 0, stream>>>(hB, part + (size_t)nckH * 2 * HH, HH);
    bn_stats_final<<<dim3(HH / 256), blk, 0, stream>>>(part, stat, HH, nck);
    bn_lif_scan_pack<<<dim3(HH / 256, BB / 2), blk, 0, stream>>>(
        hA, spk, stat, g2, bi2, bp2, U02, HH);
    bn_lif_scan_pack<<<dim3(HH / 256, BB / 2), blk, 0, stream>>>(
        hB, spk + (size_t)MHALF * (HH / 64), stat, g2, bi2, bp2, U02 + (size_t)(BB / 2) * HH, HH);

    // ================= Layer 3: spk[M,H] * W3[J,H]^T (MFMA bf16x3) =======
    mfma_spk_gemm<<<dim3(MM / 128, JJ / 128), blk, 0, stream>>>(
        (const unsigned char*)spk, W3h, W3m, W3l, hA, MM, JJ, HH);
    bn_stats_partial<<<dim3(JJ / 256, nck), blk, 0, stream>>>(hA, part, JJ);
    bn_stats_final<<<dim3(JJ / 256), blk, 0, stream>>>(part, stat, JJ, nck);
    bn_lif_scan_f32<<<dim3(JJ / 256, BB), blk, 0, stream>>>(
        hA, out, stat, g3, bi3, bp3, U03, JJ);
}

// Round 7
// 5094.183 us; speedup vs baseline: 1.2366x; 1.0283x over previous
//
#include <hip/hip_runtime.h>
#include <hip/hip_bf16.h>
#include <cmath>

// Problem constants: B=32, T=1024, J=1024, H=2048
#define BB 32
#define TT 1024
#define JJ 1024
#define HH 2048
#define MM (BB * TT)      // 32768 rows
#define MHALF (MM / 2)    // 16384

typedef short s8v __attribute__((ext_vector_type(8)));   // 8 bf16 raw
typedef float f4v __attribute__((ext_vector_type(4)));
typedef unsigned int u4v __attribute__((ext_vector_type(4)));
union ABu { u4v u; s8v v; };

// ============ exact f32 -> bf16 hi/mid/lo (w == h+m+l exactly) ============
__device__ inline void split_bf16x3(float w, unsigned short& h,
                                    unsigned short& m, unsigned short& l) {
    __hip_bfloat16 bh = __float2bfloat16(w);
    const float fh = __bfloat162float(bh);
    const float r1 = w - fh;                  // exact
    __hip_bfloat16 bm = __float2bfloat16(r1);
    const float fm = __bfloat162float(bm);
    __hip_bfloat16 bl = __float2bfloat16(r1 - fm);  // exact residual (8 bits left)
    h = *(unsigned short*)&bh; m = *(unsigned short*)&bm; l = *(unsigned short*)&bl;
}

__global__ void split_w(const float* __restrict__ W,
                        unsigned short* __restrict__ ph,
                        unsigned short* __restrict__ pm,
                        unsigned short* __restrict__ pl, int n)
{
    const int i = blockIdx.x * 256 + threadIdx.x;
    if (i >= n) return;
    split_bf16x3(W[i], ph[i], pm[i], pl[i]);
}

// ============ spike MFMA GEMM — BK=64 (THE ONLY CHANGE THIS ROUND) ========
// Exact: spikes {0,1} exact in bf16; W = Wh+Wm+Wl exact. Same per-32-chunk
// swizzle as the R3-proven BK=32 version; two k-halves per LDS buffer.
__global__ __launch_bounds__(256) void mfma_spk_gemm(
    const unsigned char* __restrict__ S,    // [M, K/8] bit-packed spikes
    const unsigned short* __restrict__ Wh,  // [N,K] bf16 raw
    const unsigned short* __restrict__ Wm,
    const unsigned short* __restrict__ Wl,
    float* __restrict__ C, int M, int N, int K)
{
    __shared__ __align__(16) unsigned short Blds[3][2][128][32];  // 48 KB
    const int tid = threadIdx.x;
    const int wv = tid >> 6;
    const int lane = tid & 63;
    const int wm = wv >> 1, wn = wv & 1;
    const int r16 = lane & 15, quad = lane >> 4;
    const int bm = blockIdx.x * 128;
    const int bn = blockIdx.y * 128;
    const int Kb = K >> 3;

    f4v acc[4][4] = {};

    const int rl = lane >> 2, chl = lane & 3;
    size_t soff[2];
    int ldsrow[2];
#pragma unroll
    for (int i = 0; i < 2; ++i) {
        const int r = wv * 32 + i * 16 + rl;
        const int kc = (chl - (r >> 1)) & 3;
        soff[i] = (size_t)(bn + r) * K + kc * 8;   // ushort units
        ldsrow[i] = wv * 32 + i * 16;
    }

    size_t aoff[4];
#pragma unroll
    for (int ms = 0; ms < 4; ++ms)
        aoff[ms] = (size_t)(bm + wm * 64 + ms * 16 + r16) * Kb + quad;

    int bR[4], bC[4];
#pragma unroll
    for (int ns = 0; ns < 4; ++ns) {
        bR[ns] = wn * 64 + ns * 16 + r16;
        bC[ns] = ((quad + (bR[ns] >> 1)) & 3) * 8;
    }

    // preload first tile's A bytes (k-chunks kh*32: byte offset kh*4)
    unsigned int ab[2][4];
#pragma unroll
    for (int kh = 0; kh < 2; ++kh)
#pragma unroll
        for (int ms = 0; ms < 4; ++ms) ab[kh][ms] = S[aoff[ms] + kh * 4];

    for (int k0 = 0; k0 < K; k0 += 64) {
        __syncthreads();
#pragma unroll
        for (int i = 0; i < 2; ++i)
#pragma unroll
            for (int kh = 0; kh < 2; ++kh) {
                __builtin_amdgcn_global_load_lds(
                    (const __attribute__((address_space(1))) void*)(Wh + soff[i] + k0 + kh * 32),
                    (__attribute__((address_space(3))) void*)&Blds[0][kh][ldsrow[i]][0], 16, 0, 0);
                __builtin_amdgcn_global_load_lds(
                    (const __attribute__((address_space(1))) void*)(Wm + soff[i] + k0 + kh * 32),
                    (__attribute__((address_space(3))) void*)&Blds[1][kh][ldsrow[i]][0], 16, 0, 0);
                __builtin_amdgcn_global_load_lds(
                    (const __attribute__((address_space(1))) void*)(Wl + soff[i] + k0 + kh * 32),
                    (__attribute__((address_space(3))) void*)&Blds[2][kh][ldsrow[i]][0], 16, 0, 0);
            }
        // unpack current A bytes -> bf16 fragments
        s8v afr[2][4];
#pragma unroll
        for (int kh = 0; kh < 2; ++kh)
#pragma unroll
            for (int ms = 0; ms < 4; ++ms) {
                ABu t;
                const unsigned int b = ab[kh][ms];
                t.u[0] = ((b        & 1u) * 0x3F80u) | (((b >> 1) & 1u) * 0x3F800000u);
                t.u[1] = (((b >> 2) & 1u) * 0x3F80u) | (((b >> 3) & 1u) * 0x3F800000u);
                t.u[2] = (((b >> 4) & 1u) * 0x3F80u) | (((b >> 5) & 1u) * 0x3F800000u);
                t.u[3] = (((b >> 6) & 1u) * 0x3F80u) | (((b >> 7) & 1u) * 0x3F800000u);
                afr[kh][ms] = t.v;
            }
        // prefetch next tile's A bytes (global only — no LDS hazard)
        if (k0 + 64 < K) {
            const size_t kb = (size_t)((k0 + 64) >> 3);
#pragma unroll
            for (int kh = 0; kh < 2; ++kh)
#pragma unroll
                for (int ms = 0; ms < 4; ++ms) ab[kh][ms] = S[aoff[ms] + kb + kh * 4];
        }
        __syncthreads();
#pragma unroll
        for (int p = 0; p < 3; ++p)
#pragma unroll
            for (int kh = 0; kh < 2; ++kh) {
                s8v bf[4];
#pragma unroll
                for (int ns = 0; ns < 4; ++ns)
                    bf[ns] = *(const s8v*)&Blds[p][kh][bR[ns]][bC[ns]];
#pragma unroll
                for (int ms = 0; ms < 4; ++ms)
#pragma unroll
                    for (int ns = 0; ns < 4; ++ns)
                        acc[ms][ns] = __builtin_amdgcn_mfma_f32_16x16x32_bf16(
                            afr[kh][ms], bf[ns], acc[ms][ns], 0, 0, 0);
            }
    }

#pragma unroll
    for (int ms = 0; ms < 4; ++ms)
#pragma unroll
        for (int ns = 0; ns < 4; ++ns) {
            const int row = bm + wm * 64 + ms * 16 + quad * 4;
            const int col = bn + wn * 64 + ns * 16 + r16;
#pragma unroll
            for (int r = 0; r < 4; ++r)
                C[(size_t)(row + r) * N + col] = acc[ms][ns][r];
        }
}

// ============ f32 SGEMM for layer 1 (ROUND-3 PROVEN VERSION) ==============
#define BM 128
#define BN 128
#define BK 16
#define LDS_LD 132

__global__ __launch_bounds__(256) void sgemm_bt(
    const float* __restrict__ A,   // [M,K]
    const float* __restrict__ W,   // [N,K]
    float* __restrict__ C,         // [M,N]
    int M, int N, int K)
{
    __shared__ float As[BK][LDS_LD];
    __shared__ float Bs[BK][LDS_LD];
    const int tid = threadIdx.x;
    const int tx = tid & 15;
    const int ty = tid >> 4;
    const int bm = blockIdx.x * BM;
    const int bn = blockIdx.y * BN;

    float acc[8][8];
#pragma unroll
    for (int i = 0; i < 8; ++i)
#pragma unroll
        for (int j = 0; j < 8; ++j) acc[i][j] = 0.f;

    const int r0 = tid >> 2;
    const int c4 = (tid & 3) * 4;

    for (int k0 = 0; k0 < K; k0 += BK) {
#pragma unroll
        for (int l = 0; l < 2; ++l) {
            const int r = r0 + l * 64;
            const float4 va = *(const float4*)(A + (size_t)(bm + r) * K + k0 + c4);
            As[c4 + 0][r] = va.x; As[c4 + 1][r] = va.y;
            As[c4 + 2][r] = va.z; As[c4 + 3][r] = va.w;
            const float4 vb = *(const float4*)(W + (size_t)(bn + r) * K + k0 + c4);
            Bs[c4 + 0][r] = vb.x; Bs[c4 + 1][r] = vb.y;
            Bs[c4 + 2][r] = vb.z; Bs[c4 + 3][r] = vb.w;
        }
        __syncthreads();
#pragma unroll
        for (int k = 0; k < BK; ++k) {
            float a[8], b[8];
            *(float4*)&a[0] = *(const float4*)&As[k][ty * 8];
            *(float4*)&a[4] = *(const float4*)&As[k][ty * 8 + 4];
            *(float4*)&b[0] = *(const float4*)&Bs[k][tx * 4];
            *(float4*)&b[4] = *(const float4*)&Bs[k][64 + tx * 4];
#pragma unroll
            for (int i = 0; i < 8; ++i)
#pragma unroll
                for (int j = 0; j < 8; ++j)
                    acc[i][j] = fmaf(a[i], b[j], acc[i][j]);
        }
        __syncthreads();
    }
#pragma unroll
    for (int i = 0; i < 8; ++i) {
        const size_t row = (size_t)(bm + ty * 8 + i) * N;
        *(float4*)(C + row + bn + tx * 4)      = make_float4(acc[i][0], acc[i][1], acc[i][2], acc[i][3]);
        *(float4*)(C + row + bn + 64 + tx * 4) = make_float4(acc[i][4], acc[i][5], acc[i][6], acc[i][7]);
    }
}

// ============ BatchNorm stats (ROUND-3 VERSION) ===========================
#define RCHUNK 128

__global__ void bn_stats_partial(const float* __restrict__ h,
                                 float* __restrict__ partial, int N)
{
    const int n = blockIdx.x * 256 + threadIdx.x;
    const int chunk = blockIdx.y;
    const float* p = h + (size_t)chunk * RCHUNK * N + n;
    float s = 0.f, s2 = 0.f;
#pragma unroll 4
    for (int r = 0; r < RCHUNK; ++r) {
        const float v = p[(size_t)r * N];
        s += v;
        s2 = fmaf(v, v, s2);
    }
    partial[((size_t)chunk * 2 + 0) * N + n] = s;
    partial[((size_t)chunk * 2 + 1) * N + n] = s2;
}

__global__ void bn_stats_final(const float* __restrict__ partial,
                               float* __restrict__ stats,
                               int N, int nchunks)
{
    const int n = blockIdx.x * 256 + threadIdx.x;
    double s = 0.0, s2 = 0.0;
    for (int c = 0; c < nchunks; ++c) {
        s  += (double)partial[((size_t)c * 2 + 0) * N + n];
        s2 += (double)partial[((size_t)c * 2 + 1) * N + n];
    }
    const double inv_m = 1.0 / (double)MM;
    const double mu = s * inv_m;
    const double var = s2 * inv_m - mu * mu;
    stats[n]     = (float)mu;
    stats[N + n] = (float)(1.0 / sqrt(var + 1e-5));
}

// ============ fused BN + LIF scan (ROUND-3 VERSION) =======================
__global__ void bn_lif_scan_pack(const float* __restrict__ h,       // [nb*T, N]
                                 unsigned long long* __restrict__ bits,
                                 const float* __restrict__ stats,
                                 const float* __restrict__ gamma,
                                 const float* __restrict__ bias,
                                 const float* __restrict__ beta_p,
                                 const float* __restrict__ U0,      // [nb, N]
                                 int N)
{
    const int n = blockIdx.x * 256 + threadIdx.x;
    const int b = blockIdx.y;
    const int nw = N >> 6;
    const float mu = stats[n];
    const float rstd = stats[N + n];
    const float g = gamma[n];
    const float bi = bias[n];
    const float beta = 1.f / (1.f + expf(-beta_p[n]));
    const float omb = 1.f - beta;
    float u = U0[(size_t)b * N + n];
    float s = 0.f;
    size_t idx = ((size_t)b * TT) * N + n;
    size_t widx = ((size_t)b * TT) * nw + (n >> 6);
    const bool lead = (threadIdx.x & 63) == 0;
    for (int t = 0; t < TT; ++t, idx += N, widx += nw) {
        const float hn = (h[idx] - mu) * rstd * g + bi;
        u = beta * (u - s) + omb * hn;
        const bool sp = (u - 1.0f) >= 0.f;
        s = sp ? 1.f : 0.f;
        const unsigned long long m = __ballot(sp);
        if (lead) bits[widx] = m;
    }
}

__global__ void bn_lif_scan_f32(const float* __restrict__ h,
                                float* __restrict__ out,
                                const float* __restrict__ stats,
                                const float* __restrict__ gamma,
                                const float* __restrict__ bias,
                                const float* __restrict__ beta_p,
                                const float* __restrict__ U0,
                                int N)
{
    const int n = blockIdx.x * 256 + threadIdx.x;
    const int b = blockIdx.y;
    const float mu = stats[n];
    const float rstd = stats[N + n];
    const float g = gamma[n];
    const float bi = bias[n];
    const float beta = 1.f / (1.f + expf(-beta_p[n]));
    const float omb = 1.f - beta;
    float u = U0[(size_t)b * N + n];
    float s = 0.f;
    size_t idx = ((size_t)b * TT) * N + n;
    for (int t = 0; t < TT; ++t, idx += N) {
        const float hn = (h[idx] - mu) * rstd * g + bi;
        u = beta * (u - s) + omb * hn;
        s = ((u - 1.0f) >= 0.f) ? 1.f : 0.f;
        out[idx] = s;
    }
}

// ============ launcher (ROUND-3 VERSION, W1 split removed) ================
extern "C" void kernel_launch(void* const* d_in, const int* in_sizes, int n_in,
                              void* d_out, int out_size, void* d_ws, size_t ws_size,
                              hipStream_t stream)
{
    const float* x   = (const float*)d_in[0];
    const float* W1  = (const float*)d_in[1];
    const float* bp1 = (const float*)d_in[2];
    const float* g1  = (const float*)d_in[3];
    const float* bi1 = (const float*)d_in[4];
    const float* U01 = (const float*)d_in[5];
    const float* W2  = (const float*)d_in[6];
    const float* bp2 = (const float*)d_in[7];
    const float* g2  = (const float*)d_in[8];
    const float* bi2 = (const float*)d_in[9];
    const float* U02 = (const float*)d_in[10];
    const float* W3  = (const float*)d_in[11];
    const float* bp3 = (const float*)d_in[12];
    const float* g3  = (const float*)d_in[13];
    const float* bi3 = (const float*)d_in[14];
    const float* U03 = (const float*)d_in[15];
    float* out = (float*)d_out;

    // ws layout (R3-proven, ~185 MB): hA | spk | part | stat | W2/W3 planes
    unsigned char* ws = (unsigned char*)d_ws;
    const size_t HA_BYTES  = (size_t)MHALF * HH * sizeof(float);  // 134217728
    const size_t SPK_BYTES = (size_t)MM * (HH / 8);               // 8388608
    float*              hA   = (float*)ws;
    float*              hB   = (float*)d_out;  // scratch until final scan
    unsigned long long* spk  = (unsigned long long*)(ws + HA_BYTES);
    float*              part = (float*)(ws + HA_BYTES + SPK_BYTES);
    float*              stat = (float*)(ws + HA_BYTES + SPK_BYTES + 4194304);
    unsigned short*     W2h  = (unsigned short*)(ws + HA_BYTES + SPK_BYTES + 4194304 + 16384);
    unsigned short*     W2m  = W2h + (size_t)HH * HH;
    unsigned short*     W2l  = W2m + (size_t)HH * HH;
    unsigned short*     W3h  = W2l + (size_t)HH * HH;
    unsigned short*     W3m  = W3h + (size_t)JJ * HH;
    unsigned short*     W3l  = W3m + (size_t)JJ * HH;

    const dim3 blk(256);
    const int nck  = MM / RCHUNK;      // 256
    const int nckH = MHALF / RCHUNK;   // 128

    split_w<<<dim3((HH * HH) / 256), blk, 0, stream>>>(W2, W2h, W2m, W2l, HH * HH);
    split_w<<<dim3((JJ * HH) / 256), blk, 0, stream>>>(W3, W3h, W3m, W3l, JJ * HH);

    // ---- Layer 1: x[M,J] * W1[H,J]^T (f32 vector GEMM, proven) ----
    sgemm_bt<<<dim3(MHALF / BM, HH / BN), blk, 0, stream>>>(x, W1, hA, MHALF, HH, JJ);
    sgemm_bt<<<dim3(MHALF / BM, HH / BN), blk, 0, stream>>>(
        x + (size_t)MHALF * JJ, W1, hB, MHALF, HH, JJ);
    bn_stats_partial<<<dim3(HH / 256, nckH), blk, 0, stream>>>(hA, part, HH);
    bn_stats_partial<<<dim3(HH / 256, nckH), blk, 0, stream>>>(hB, part + (size_t)nckH * 2 * HH, HH);
    bn_stats_final<<<dim3(HH / 256), blk, 0, stream>>>(part, stat, HH, nck);
    bn_lif_scan_pack<<<dim3(HH / 256, BB / 2), blk, 0, stream>>>(
        hA, spk, stat, g1, bi1, bp1, U01, HH);
    bn_lif_scan_pack<<<dim3(HH / 256, BB / 2), blk, 0, stream>>>(
        hB, spk + (size_t)MHALF * (HH / 64), stat, g1, bi1, bp1, U01 + (size_t)(BB / 2) * HH, HH);

    // ---- Layer 2: spk[M,H] * W2[H,H]^T (MFMA bf16x3, BK=64, per half) ----
    mfma_spk_gemm<<<dim3(MHALF / 128, HH / 128), blk, 0, stream>>>(
        (const unsigned char*)spk, W2h, W2m, W2l, hA, MHALF, HH, HH);
    mfma_spk_gemm<<<dim3(MHALF / 128, HH / 128), blk, 0, stream>>>(
        (const unsigned char*)spk + (size_t)MHALF * (HH / 8), W2h, W2m, W2l, hB, MHALF, HH, HH);
    bn_stats_partial<<<dim3(HH / 256, nckH), blk, 0, stream>>>(hA, part, HH);
    bn_stats_partial<<<dim3(HH / 256, nckH), blk, 0, stream>>>(hB, part + (size_t)nckH * 2 * HH, HH);
    bn_stats_final<<<dim3(HH / 256), blk, 0, stream>>>(part, stat, HH, nck);
    bn_lif_scan_pack<<<dim3(HH / 256, BB / 2), blk, 0, stream>>>(
        hA, spk, stat, g2, bi2, bp2, U02, HH);
    bn_lif_scan_pack<<<dim3(HH / 256, BB / 2), blk, 0, stream>>>(
        hB, spk + (size_t)MHALF * (HH / 64), stat, g2, bi2, bp2, U02 + (size_t)(BB / 2) * HH, HH);

    // ---- Layer 3: spk[M,H] * W3[J,H]^T -> hA [M,1024] ----
    mfma_spk_gemm<<<dim3(MM / 128, JJ / 128), blk, 0, stream>>>(
        (const unsigned char*)spk, W3h, W3m, W3l, hA, MM, JJ, HH);
    bn_stats_partial<<<dim3(JJ / 256, nck), blk, 0, stream>>>(hA, part, JJ);
    bn_stats_final<<<dim3(JJ / 256), blk, 0, stream>>>(part, stat, JJ, nck);
    bn_lif_scan_f32<<<dim3(JJ / 256, BB), blk, 0, stream>>>(
        hA, out, stat, g3, bi3, bp3, U03, JJ);
}